// Round 18
// baseline (83.772 us; speedup 1.0000x reference)
//
#include <hip/hip_runtime.h>
#include <stdint.h>

// RelationTransform: out[i] = W[relation[i]] @ node_emb[i]
// N=32768, EMB=512, 16 relations, fp32 in/out.
// Prepass (3 launches): {block-histogram || convert W->bf16} fused in one
// kernel, then prefix (1 block), then ptok scatter. No init kernel (the
// block-histogram is atomic-free on globals).
// GEMM gg18 = gg13's kernel byte-for-byte (best measured: 65.4 total):
// fused-A (fp32 X reg-gather via ptok -> cvt -> swizzled ds_write),
// prestaged-B (bf16 Ws via gload_lds), 128x256, 512 thr, ring-3 (72KB),
// counted vmcnt(8), verified 0-conflict granule swizzle, ct-minor chunked
// XCD lids.

#define EMB 512
#define N_RELC 16
#define BM 128
#define BN 256
#define BK 32
#define NKT 16

typedef __attribute__((ext_vector_type(4))) float f32x4;
typedef __attribute__((ext_vector_type(8))) short bf16x8;

__device__ __forceinline__ unsigned short f2bf(float f) {
  unsigned int u = __float_as_uint(f);
  u += 0x7FFFu + ((u >> 16) & 1u);   // round-to-nearest-even
  return (unsigned short)(u >> 16);
}

__device__ __forceinline__ bf16x8 cvt8(f32x4 lo, f32x4 hi) {
  bf16x8 o;
  o[0] = (short)f2bf(lo[0]); o[1] = (short)f2bf(lo[1]);
  o[2] = (short)f2bf(lo[2]); o[3] = (short)f2bf(lo[3]);
  o[4] = (short)f2bf(hi[0]); o[5] = (short)f2bf(hi[1]);
  o[6] = (short)f2bf(hi[2]); o[7] = (short)f2bf(hi[3]);
  return o;
}

__device__ __forceinline__ void gload_lds16(const void* g, void* l) {
  __builtin_amdgcn_global_load_lds(
      (const __attribute__((address_space(1))) unsigned int*)(uintptr_t)g,
      (__attribute__((address_space(3))) unsigned int*)(uintptr_t)l, 16, 0, 0);
}

// Fused: blocks [0,gpad) = atomic-free block histogram (per-block counts to
// blockcnt, within-block rank to pos, ptok=-1 fill); blocks [gpad,..) =
// convert W -> bf16 Ws. (histo part verified in round 15; hides under convW.)
__global__ __launch_bounds__(256) void prep1(
    const int* __restrict__ rel, const float* __restrict__ W,
    int* __restrict__ blockcnt, int* __restrict__ pos, int* __restrict__ ptok,
    unsigned short* __restrict__ Ws,
    int n, int padn, int nbh, int welems, int gpad)
{
  const int b = blockIdx.x;
  const int tid = threadIdx.x;
  if (b < gpad) {
    __shared__ int lcnt[N_RELC];
    if (tid < N_RELC) lcnt[tid] = 0;
    __syncthreads();
    const int i = b * 256 + tid;
    if (i < padn) ptok[i] = -1;
    if (i < n) pos[i] = atomicAdd(&lcnt[rel[i]], 1);
    __syncthreads();
    if (b < nbh && tid < N_RELC) blockcnt[b * N_RELC + tid] = lcnt[tid];
  } else {
    const size_t i = (((size_t)(b - gpad)) * 256 + tid) * 8;
    if (i >= (size_t)welems) return;
    f32x4 a = *reinterpret_cast<const f32x4*>(W + i);
    f32x4 c = *reinterpret_cast<const f32x4*>(W + i + 4);
    bf16x8 o;
    o[0] = f2bf(a[0]); o[1] = f2bf(a[1]); o[2] = f2bf(a[2]); o[3] = f2bf(a[3]);
    o[4] = f2bf(c[0]); o[5] = f2bf(c[1]); o[6] = f2bf(c[2]); o[7] = f2bf(c[3]);
    *reinterpret_cast<bf16x8*>(Ws + i) = o;
  }
}

// 1 block: totals, padded bases, tile table, per-block scatter bases.
__global__ __launch_bounds__(64) void prefix2(
    const int* __restrict__ blockcnt, int* __restrict__ pbase,
    int* __restrict__ bbase, int* __restrict__ tinfo, int nbh, int maxt) {
  __shared__ int sc[N_RELC];
  __shared__ int sb[N_RELC + 1];
  __shared__ int st[N_RELC + 1];
  const int tid = threadIdx.x;
  if (tid < N_RELC) {
    int s = 0;
    for (int b = 0; b < nbh; ++b) s += blockcnt[b * N_RELC + tid];
    sc[tid] = s;
  }
  __syncthreads();
  if (tid == 0) {
    int acc = 0, t = 0;
    for (int r = 0; r < N_RELC; ++r) {
      sb[r] = acc; st[r] = t;
      const int nt = (sc[r] + BM - 1) / BM;
      acc += nt * BM;
      t += nt;
    }
    sb[N_RELC] = acc; st[N_RELC] = t;
  }
  __syncthreads();
  if (tid < N_RELC) {
    int run = sb[tid];
    for (int b = 0; b < nbh; ++b) {
      bbase[b * N_RELC + tid] = run;
      run += blockcnt[b * N_RELC + tid];
    }
    pbase[tid] = sb[tid];
  }
  if (tid == 0) pbase[N_RELC] = sb[N_RELC];
  for (int x = tid; x < maxt; x += 64) {
    int v = -1;
    #pragma unroll
    for (int r = 0; r < N_RELC; ++r)
      if (x >= st[r] && x < st[r + 1]) v = (r << 16) | (x - st[r]);
    tinfo[x] = v;
  }
}

__global__ __launch_bounds__(256) void scatter2(
    const int* __restrict__ rel, const int* __restrict__ pos,
    const int* __restrict__ bbase, int* __restrict__ ptok, int n) {
  const int i = blockIdx.x * blockDim.x + threadIdx.x;
  if (i < n) ptok[bbase[(i >> 8) * N_RELC + rel[i]] + pos[i]] = i;
}

// ---------------------------------------------------------------------------
// gg18 (= gg13's GEMM). LDS ring-3: As bf16 [128][32] 8KB, Bs bf16
// [256][32] 16KB (72KB). Rows 64B = 4x16B granules, phys = log^((row>>1)&3)
// (verified 0-conflict). A: tile k regs (2x dwordx4 fp32, ptok-gathered)
// loaded at ITER(k-2), cvt+swizzled ds_write at ITER(k-1) post-barrier,
// computed at ITER(k). B: 2x gload_lds per slab from Ws.
// ITER(t): ALOAD(t+2); BSTAGE(t+2); vmcnt(8); barrier; AWRITE(t+1);
// COMPUTE(t); lgkm(0); barrier. Tail vmcnt 4 -> 0.
// ---------------------------------------------------------------------------

#define ALOAD(P, KT)                                                           \
  {                                                                            \
    const float* ap_ = aptr + (KT) * BK;                                       \
    a##P##0 = *reinterpret_cast<const f32x4*>(ap_);                            \
    a##P##1 = *reinterpret_cast<const f32x4*>(ap_ + 4);                        \
  }

#define AWRITE(S, P)                                                           \
  {                                                                            \
    bf16x8 w_ = cvt8(a##P##0, a##P##1);                                        \
    *reinterpret_cast<bf16x8*>((char*)&As[S][0] + awoff) = w_;                 \
  }

#define BSTAGE(S, KT)                                                          \
  {                                                                            \
    const int kb_ = (KT) * BK;                                                 \
    gload_lds16(bsrc0 + kb_, (char*)&Bs[S][0] + tid * 16);                     \
    gload_lds16(bsrc1 + kb_, (char*)&Bs[S][0] + 8192 + tid * 16);              \
  }

#define COMPUTE(S)                                                             \
  {                                                                            \
    bf16x8 af[4], bfr[4];                                                      \
    _Pragma("unroll")                                                          \
    for (int m = 0; m < 4; ++m) {                                              \
      const int rr_ = wr * 64 + m * 16 + lrow;                                 \
      af[m] = *reinterpret_cast<const bf16x8*>(                                \
          (const char*)&As[S][0] + rr_ * 64 + ((gl ^ ((rr_ >> 1) & 3)) * 16)); \
    }                                                                          \
    _Pragma("unroll")                                                          \
    for (int nn = 0; nn < 4; ++nn) {                                           \
      const int rw_ = wc * 64 + nn * 16 + lrow;                                \
      bfr[nn] = *reinterpret_cast<const bf16x8*>(                              \
          (const char*)&Bs[S][0] + rw_ * 64 + ((gl ^ ((rw_ >> 1) & 3)) * 16)); \
    }                                                                          \
    __builtin_amdgcn_s_setprio(1);                                             \
    _Pragma("unroll")                                                          \
    for (int m = 0; m < 4; ++m)                                                \
      _Pragma("unroll")                                                        \
      for (int nn = 0; nn < 4; ++nn)                                           \
        acc[m][nn] = __builtin_amdgcn_mfma_f32_16x16x32_bf16(                  \
            af[m], bfr[nn], acc[m][nn], 0, 0, 0);                              \
    __builtin_amdgcn_s_setprio(0);                                             \
  }

#define ITER(T, VM)                                                            \
  {                                                                            \
    if ((T) + 2 < NKT) {                                                       \
      if (((T) & 1) == 0) ALOAD(e, (T) + 2) else ALOAD(o, (T) + 2)             \
      __builtin_amdgcn_sched_barrier(0);                                       \
      BSTAGE(((T) + 2) % 3, (T) + 2);                                          \
      __builtin_amdgcn_sched_barrier(0);                                       \
    }                                                                          \
    asm volatile("s_waitcnt vmcnt(" #VM ")" ::: "memory");                     \
    __builtin_amdgcn_s_barrier();                                              \
    __builtin_amdgcn_sched_barrier(0);                                         \
    if ((T) + 1 < NKT) {                                                       \
      if ((((T) + 1) & 1) == 0) AWRITE(((T) + 1) % 3, e)                       \
      else                      AWRITE(((T) + 1) % 3, o)                       \
    }                                                                          \
    COMPUTE((T) % 3);                                                          \
    asm volatile("s_waitcnt lgkmcnt(0)" ::: "memory");                         \
    __builtin_amdgcn_s_barrier();                                              \
    __builtin_amdgcn_sched_barrier(0);                                         \
  }

__global__ __launch_bounds__(512, 4) void gg18(
    const float* __restrict__ X, const unsigned short* __restrict__ Ws,
    const int* __restrict__ pbase, const int* __restrict__ tinfo,
    const int* __restrict__ ptok, float* __restrict__ out)
{
  __shared__ unsigned short As[3][BM * BK];   // 3 x 8 KB
  __shared__ unsigned short Bs[3][BN * BK];   // 3 x 16 KB  (72 KB total)

  // Chunked bijective XCD swizzle (gridDim.x % 8 == 0); lid = mtile*2 + ct.
  const int q = gridDim.x >> 3;
  const int lid = ((int)blockIdx.x & 7) * q + ((int)blockIdx.x >> 3);
  const int info = tinfo[lid >> 1];
  if (info < 0) return;
  const int r = info >> 16;
  const int mt = info & 0xFFFF;
  const int ct = lid & 1;
  const int prow0 = pbase[r] + mt * BM;

  const int tid = threadIdx.x;
  const int lane = tid & 63;
  const int wid = tid >> 6;
  const int wr = wid >> 2;          // 0..1 : 64-row band
  const int wc = wid & 3;           // 0..3 : 64-col band
  const int lrow = lane & 15;
  const int gl = lane >> 4;         // k-granule 0..3

  // A (fused): thread -> row srow, logical granule lg; swizzled LDS offset.
  const int srow = tid >> 2;
  const int lg = tid & 3;
  const int awoff = srow * 64 + ((lg ^ ((srow >> 1) & 3)) * 16);
  int tokA = ptok[prow0 + srow];
  if (tokA < 0) tokA = 0;           // pad rows read token 0 (discarded)
  const float* aptr = X + (size_t)tokA * EMB + lg * 8;

  // B: linear dest, inverse-swizzled source granule (verified).
  const int blg = (tid & 3) ^ ((tid >> 3) & 3);
  const unsigned short* bsrc0 =
      Ws + ((size_t)r * EMB + (size_t)(ct * BN + srow)) * EMB + blg * 8;
  const unsigned short* bsrc1 = bsrc0 + (size_t)128 * EMB;

  f32x4 acc[4][4];
  const f32x4 vzero = {0.f, 0.f, 0.f, 0.f};
  #pragma unroll
  for (int m = 0; m < 4; ++m)
    #pragma unroll
    for (int nn = 0; nn < 4; ++nn) acc[m][nn] = vzero;

  f32x4 ae0, ae1, ao0, ao1;

  // Prologue: tiles 0,1 in flight (A regs + B slabs), slab0 A written.
  ALOAD(e, 0)
  __builtin_amdgcn_sched_barrier(0);
  BSTAGE(0, 0);
  __builtin_amdgcn_sched_barrier(0);
  ALOAD(o, 1)
  __builtin_amdgcn_sched_barrier(0);
  BSTAGE(1, 1);
  __builtin_amdgcn_sched_barrier(0);
  AWRITE(0, e)                      // compiler reg-dep waits tile-0 A loads

  ITER(0, 8)   ITER(1, 8)   ITER(2, 8)   ITER(3, 8)
  ITER(4, 8)   ITER(5, 8)   ITER(6, 8)   ITER(7, 8)
  ITER(8, 8)   ITER(9, 8)   ITER(10, 8)  ITER(11, 8)
  ITER(12, 8)  ITER(13, 8)  ITER(14, 4)  ITER(15, 0)

  // Epilogue: D mapping col=lane&15, row=(lane>>4)*4+reg
  #pragma unroll
  for (int m = 0; m < 4; ++m) {
    const int base = prow0 + wr * 64 + m * 16 + gl * 4;
    #pragma unroll
    for (int rg = 0; rg < 4; ++rg) {
      const int tok = ptok[base + rg];
      if (tok >= 0) {
        float* orow = out + (size_t)tok * EMB + ct * BN + wc * 64;
        #pragma unroll
        for (int nn = 0; nn < 4; ++nn)
          orow[nn * 16 + lrow] = acc[m][nn][rg];
      }
    }
  }
}

// Safety-net naive kernel (only if ws too small).
__global__ void naive_kernel(const float* __restrict__ X, const int* __restrict__ rel,
                             const float* __restrict__ W, float* __restrict__ out, int n) {
  int i = blockIdx.x;
  if (i >= n) return;
  int r = rel[i];
  const float* x = X + (size_t)i * EMB;
  const float* Wr = W + (size_t)r * EMB * EMB;
  for (int j = threadIdx.x; j < EMB; j += blockDim.x) {
    const float* w = Wr + (size_t)j * EMB;
    float s = 0.f;
    for (int k = 0; k < EMB; ++k) s += w[k] * x[k];
    out[(size_t)i * EMB + j] = s;
  }
}

extern "C" void kernel_launch(void* const* d_in, const int* in_sizes, int n_in,
                              void* d_out, int out_size, void* d_ws, size_t ws_size,
                              hipStream_t stream) {
  const float* X  = (const float*)d_in[0];
  const int* rel  = (const int*)d_in[1];
  const float* W  = (const float*)d_in[2];
  float* out      = (float*)d_out;
  const int n = in_sizes[1];
  const int welems = in_sizes[2];                 // n_rel * EMB * EMB
  const int padn = n + N_RELC * BM;
  const int nbh = (n + 255) / 256;                // histo blocks with tokens
  const int gpad = (padn + 255) / 256;            // histo grid (ptok fill)
  const int maxt = (n + BM - 1) / BM + N_RELC;
  const int maxtp = ((maxt + 3) / 4) * 4;         // grid = 2*maxtp -> %8==0

  const size_t ints = (size_t)32 + n + padn + maxtp + 2 * (size_t)nbh * N_RELC;
  const size_t offW = ((ints * sizeof(int) + 255) / 256) * 256;
  const size_t need = offW + (size_t)welems * 2;

  if (ws_size < need) {
    naive_kernel<<<n, 256, 0, stream>>>(X, rel, W, out, n);
    return;
  }

  int* pbase    = (int*)d_ws;            // 17 (+pad to 32)
  int* pos      = pbase + 32;            // n
  int* ptok     = pos + n;               // padn
  int* tinfo    = ptok + padn;           // maxtp
  int* blockcnt = tinfo + maxtp;         // nbh*16
  int* bbase    = blockcnt + (size_t)nbh * N_RELC;  // nbh*16
  unsigned short* Ws = (unsigned short*)((char*)d_ws + offW);

  const int wb = (welems / 8 + 255) / 256;          // convert-W blocks

  prep1<<<gpad + wb, 256, 0, stream>>>(rel, W, blockcnt, pos, ptok, Ws,
                                       n, padn, nbh, welems, gpad);
  prefix2<<<1, 64, 0, stream>>>(blockcnt, pbase, bbase, tinfo, nbh, maxtp);
  scatter2<<<(n + 255) / 256, 256, 0, stream>>>(rel, pos, bbase, ptok, n);

  gg18<<<2 * maxtp, 512, 0, stream>>>(X, Ws, pbase, tinfo, ptok, out);
}

// Round 19
// 60.386 us; speedup vs baseline: 1.3873x; 1.3873x over previous
//
#include <hip/hip_runtime.h>
#include <stdint.h>

// RelationTransform: out[i] = W[relation[i]] @ node_emb[i]
// N=32768, EMB=512, 16 relations, fp32 in/out.
// Prepass (3 launches): {block-histogram || convert W->bf16} fused (prep1,
// verified r18) -> PARALLEL prefix (prefix3: chunked scan, no serial
// 128-load loops - the r18 regression) -> ptok scatter (verified r18).
// GEMM gg19 = gg13/gg18 byte-for-byte (best GEMM+prepass combo measured):
// fused-A (fp32 X reg-gather via ptok -> cvt -> swizzled ds_write),
// prestaged-B (bf16 Ws via gload_lds), 128x256, 512 thr, ring-3 (72KB),
// counted vmcnt(8), verified 0-conflict granule swizzle, ct-minor chunked
// XCD lids.

#define EMB 512
#define N_RELC 16
#define BM 128
#define BN 256
#define BK 32
#define NKT 16

typedef __attribute__((ext_vector_type(4))) float f32x4;
typedef __attribute__((ext_vector_type(8))) short bf16x8;

__device__ __forceinline__ unsigned short f2bf(float f) {
  unsigned int u = __float_as_uint(f);
  u += 0x7FFFu + ((u >> 16) & 1u);   // round-to-nearest-even
  return (unsigned short)(u >> 16);
}

__device__ __forceinline__ bf16x8 cvt8(f32x4 lo, f32x4 hi) {
  bf16x8 o;
  o[0] = (short)f2bf(lo[0]); o[1] = (short)f2bf(lo[1]);
  o[2] = (short)f2bf(lo[2]); o[3] = (short)f2bf(lo[3]);
  o[4] = (short)f2bf(hi[0]); o[5] = (short)f2bf(hi[1]);
  o[6] = (short)f2bf(hi[2]); o[7] = (short)f2bf(hi[3]);
  return o;
}

__device__ __forceinline__ void gload_lds16(const void* g, void* l) {
  __builtin_amdgcn_global_load_lds(
      (const __attribute__((address_space(1))) unsigned int*)(uintptr_t)g,
      (__attribute__((address_space(3))) unsigned int*)(uintptr_t)l, 16, 0, 0);
}

// Fused: blocks [0,gpad) = atomic-free block histogram (per-block counts to
// blockcnt, within-block rank to pos, ptok=-1 fill); blocks [gpad,..) =
// convert W -> bf16 Ws.  [verified r18: absmax passed]
__global__ __launch_bounds__(256) void prep1(
    const int* __restrict__ rel, const float* __restrict__ W,
    int* __restrict__ blockcnt, int* __restrict__ pos, int* __restrict__ ptok,
    unsigned short* __restrict__ Ws,
    int n, int padn, int nbh, int welems, int gpad)
{
  const int b = blockIdx.x;
  const int tid = threadIdx.x;
  if (b < gpad) {
    __shared__ int lcnt[N_RELC];
    if (tid < N_RELC) lcnt[tid] = 0;
    __syncthreads();
    const int i = b * 256 + tid;
    if (i < padn) ptok[i] = -1;
    if (i < n) pos[i] = atomicAdd(&lcnt[rel[i]], 1);
    __syncthreads();
    if (b < nbh && tid < N_RELC) blockcnt[b * N_RELC + tid] = lcnt[tid];
  } else {
    const size_t i = (((size_t)(b - gpad)) * 256 + tid) * 8;
    if (i >= (size_t)welems) return;
    f32x4 a = *reinterpret_cast<const f32x4*>(W + i);
    f32x4 c = *reinterpret_cast<const f32x4*>(W + i + 4);
    bf16x8 o;
    o[0] = f2bf(a[0]); o[1] = f2bf(a[1]); o[2] = f2bf(a[2]); o[3] = f2bf(a[3]);
    o[4] = f2bf(c[0]); o[5] = f2bf(c[1]); o[6] = f2bf(c[2]); o[7] = f2bf(c[3]);
    *reinterpret_cast<bf16x8*>(Ws + i) = o;
  }
}

// Parallel prefix (1 block, 256 threads): thread = (chunk c=tid>>4,
// relation r=tid&15). Phase1: parallel chunk sums (<=8 loads/thread).
// Phase2: 16 threads scan the 16 chunks in LDS. Phase3: thread 0 does the
// 16-relation padded-base/tile arithmetic. Phase4: every thread emits its
// chunk's bbase entries. Replaces r18's serial 128-load loops.
__global__ __launch_bounds__(256) void prefix3(
    const int* __restrict__ blockcnt, int* __restrict__ pbase,
    int* __restrict__ bbase, int* __restrict__ tinfo, int nbh, int maxt) {
  __shared__ int part[16][N_RELC];
  __shared__ int chpre[16][N_RELC];
  __shared__ int tot[N_RELC];
  __shared__ int sb[N_RELC + 1];
  __shared__ int st[N_RELC + 1];
  const int tid = threadIdx.x;
  const int r = tid & 15;
  const int c = tid >> 4;                 // chunk 0..15
  const int CH = (nbh + 15) / 16;
  const int b0 = c * CH;
  const int b1 = (b0 + CH < nbh) ? (b0 + CH) : nbh;
  int s = 0;
  for (int b = b0; b < b1; ++b) s += blockcnt[b * N_RELC + r];
  part[c][r] = s;
  __syncthreads();
  if (tid < N_RELC) {
    int acc = 0;
    for (int cc = 0; cc < 16; ++cc) { chpre[cc][tid] = acc; acc += part[cc][tid]; }
    tot[tid] = acc;
  }
  __syncthreads();
  if (tid == 0) {
    int acc = 0, t = 0;
    for (int rr = 0; rr < N_RELC; ++rr) {
      sb[rr] = acc; st[rr] = t;
      const int nt = (tot[rr] + BM - 1) / BM;
      acc += nt * BM;
      t += nt;
    }
    sb[N_RELC] = acc; st[N_RELC] = t;
  }
  __syncthreads();
  {
    int run = sb[r] + chpre[c][r];
    for (int b = b0; b < b1; ++b) {
      bbase[b * N_RELC + r] = run;
      run += blockcnt[b * N_RELC + r];
    }
  }
  if (tid <= N_RELC) pbase[tid] = sb[tid];
  for (int x = tid; x < maxt; x += 256) {
    int v = -1;
    #pragma unroll
    for (int rr = 0; rr < N_RELC; ++rr)
      if (x >= st[rr] && x < st[rr + 1]) v = (rr << 16) | (x - st[rr]);
    tinfo[x] = v;
  }
}

__global__ __launch_bounds__(256) void scatter2(
    const int* __restrict__ rel, const int* __restrict__ pos,
    const int* __restrict__ bbase, int* __restrict__ ptok, int n) {
  const int i = blockIdx.x * blockDim.x + threadIdx.x;
  if (i < n) ptok[bbase[(i >> 8) * N_RELC + rel[i]] + pos[i]] = i;
}

// ---------------------------------------------------------------------------
// gg19 (= gg13's GEMM, best measured). LDS ring-3: As bf16 [128][32] 8KB,
// Bs bf16 [256][32] 16KB (72KB). Rows 64B = 4x16B granules, phys =
// log^((row>>1)&3) (verified 0-conflict). A: tile k regs (2x dwordx4 fp32,
// ptok-gathered) loaded at ITER(k-2), cvt+swizzled ds_write at ITER(k-1)
// post-barrier, computed at ITER(k). B: 2x gload_lds per slab from Ws.
// ITER(t): ALOAD(t+2); BSTAGE(t+2); vmcnt(8); barrier; AWRITE(t+1);
// COMPUTE(t); lgkm(0); barrier. Tail vmcnt 4 -> 0.
// ---------------------------------------------------------------------------

#define ALOAD(P, KT)                                                           \
  {                                                                            \
    const float* ap_ = aptr + (KT) * BK;                                       \
    a##P##0 = *reinterpret_cast<const f32x4*>(ap_);                            \
    a##P##1 = *reinterpret_cast<const f32x4*>(ap_ + 4);                        \
  }

#define AWRITE(S, P)                                                           \
  {                                                                            \
    bf16x8 w_ = cvt8(a##P##0, a##P##1);                                        \
    *reinterpret_cast<bf16x8*>((char*)&As[S][0] + awoff) = w_;                 \
  }

#define BSTAGE(S, KT)                                                          \
  {                                                                            \
    const int kb_ = (KT) * BK;                                                 \
    gload_lds16(bsrc0 + kb_, (char*)&Bs[S][0] + tid * 16);                     \
    gload_lds16(bsrc1 + kb_, (char*)&Bs[S][0] + 8192 + tid * 16);              \
  }

#define COMPUTE(S)                                                             \
  {                                                                            \
    bf16x8 af[4], bfr[4];                                                      \
    _Pragma("unroll")                                                          \
    for (int m = 0; m < 4; ++m) {                                              \
      const int rr_ = wr * 64 + m * 16 + lrow;                                 \
      af[m] = *reinterpret_cast<const bf16x8*>(                                \
          (const char*)&As[S][0] + rr_ * 64 + ((gl ^ ((rr_ >> 1) & 3)) * 16)); \
    }                                                                          \
    _Pragma("unroll")                                                          \
    for (int nn = 0; nn < 4; ++nn) {                                           \
      const int rw_ = wc * 64 + nn * 16 + lrow;                                \
      bfr[nn] = *reinterpret_cast<const bf16x8*>(                              \
          (const char*)&Bs[S][0] + rw_ * 64 + ((gl ^ ((rw_ >> 1) & 3)) * 16)); \
    }                                                                          \
    __builtin_amdgcn_s_setprio(1);                                             \
    _Pragma("unroll")                                                          \
    for (int m = 0; m < 4; ++m)                                                \
      _Pragma("unroll")                                                        \
      for (int nn = 0; nn < 4; ++nn)                                           \
        acc[m][nn] = __builtin_amdgcn_mfma_f32_16x16x32_bf16(                  \
            af[m], bfr[nn], acc[m][nn], 0, 0, 0);                              \
    __builtin_amdgcn_s_setprio(0);                                             \
  }

#define ITER(T, VM)                                                            \
  {                                                                            \
    if ((T) + 2 < NKT) {                                                       \
      if (((T) & 1) == 0) ALOAD(e, (T) + 2) else ALOAD(o, (T) + 2)             \
      __builtin_amdgcn_sched_barrier(0);                                       \
      BSTAGE(((T) + 2) % 3, (T) + 2);                                          \
      __builtin_amdgcn_sched_barrier(0);                                       \
    }                                                                          \
    asm volatile("s_waitcnt vmcnt(" #VM ")" ::: "memory");                     \
    __builtin_amdgcn_s_barrier();                                              \
    __builtin_amdgcn_sched_barrier(0);                                         \
    if ((T) + 1 < NKT) {                                                       \
      if ((((T) + 1) & 1) == 0) AWRITE(((T) + 1) % 3, e)                       \
      else                      AWRITE(((T) + 1) % 3, o)                       \
    }                                                                          \
    COMPUTE((T) % 3);                                                          \
    asm volatile("s_waitcnt lgkmcnt(0)" ::: "memory");                         \
    __builtin_amdgcn_s_barrier();                                              \
    __builtin_amdgcn_sched_barrier(0);                                         \
  }

__global__ __launch_bounds__(512, 4) void gg19(
    const float* __restrict__ X, const unsigned short* __restrict__ Ws,
    const int* __restrict__ pbase, const int* __restrict__ tinfo,
    const int* __restrict__ ptok, float* __restrict__ out)
{
  __shared__ unsigned short As[3][BM * BK];   // 3 x 8 KB
  __shared__ unsigned short Bs[3][BN * BK];   // 3 x 16 KB  (72 KB total)

  // Chunked bijective XCD swizzle (gridDim.x % 8 == 0); lid = mtile*2 + ct.
  const int q = gridDim.x >> 3;
  const int lid = ((int)blockIdx.x & 7) * q + ((int)blockIdx.x >> 3);
  const int info = tinfo[lid >> 1];
  if (info < 0) return;
  const int r = info >> 16;
  const int mt = info & 0xFFFF;
  const int ct = lid & 1;
  const int prow0 = pbase[r] + mt * BM;

  const int tid = threadIdx.x;
  const int lane = tid & 63;
  const int wid = tid >> 6;
  const int wr = wid >> 2;          // 0..1 : 64-row band
  const int wc = wid & 3;           // 0..3 : 64-col band
  const int lrow = lane & 15;
  const int gl = lane >> 4;         // k-granule 0..3

  // A (fused): thread -> row srow, logical granule lg; swizzled LDS offset.
  const int srow = tid >> 2;
  const int lg = tid & 3;
  const int awoff = srow * 64 + ((lg ^ ((srow >> 1) & 3)) * 16);
  int tokA = ptok[prow0 + srow];
  if (tokA < 0) tokA = 0;           // pad rows read token 0 (discarded)
  const float* aptr = X + (size_t)tokA * EMB + lg * 8;

  // B: linear dest, inverse-swizzled source granule (verified).
  const int blg = (tid & 3) ^ ((tid >> 3) & 3);
  const unsigned short* bsrc0 =
      Ws + ((size_t)r * EMB + (size_t)(ct * BN + srow)) * EMB + blg * 8;
  const unsigned short* bsrc1 = bsrc0 + (size_t)128 * EMB;

  f32x4 acc[4][4];
  const f32x4 vzero = {0.f, 0.f, 0.f, 0.f};
  #pragma unroll
  for (int m = 0; m < 4; ++m)
    #pragma unroll
    for (int nn = 0; nn < 4; ++nn) acc[m][nn] = vzero;

  f32x4 ae0, ae1, ao0, ao1;

  // Prologue: tiles 0,1 in flight (A regs + B slabs), slab0 A written.
  ALOAD(e, 0)
  __builtin_amdgcn_sched_barrier(0);
  BSTAGE(0, 0);
  __builtin_amdgcn_sched_barrier(0);
  ALOAD(o, 1)
  __builtin_amdgcn_sched_barrier(0);
  BSTAGE(1, 1);
  __builtin_amdgcn_sched_barrier(0);
  AWRITE(0, e)                      // compiler reg-dep waits tile-0 A loads

  ITER(0, 8)   ITER(1, 8)   ITER(2, 8)   ITER(3, 8)
  ITER(4, 8)   ITER(5, 8)   ITER(6, 8)   ITER(7, 8)
  ITER(8, 8)   ITER(9, 8)   ITER(10, 8)  ITER(11, 8)
  ITER(12, 8)  ITER(13, 8)  ITER(14, 4)  ITER(15, 0)

  // Epilogue: D mapping col=lane&15, row=(lane>>4)*4+reg
  #pragma unroll
  for (int m = 0; m < 4; ++m) {
    const int base = prow0 + wr * 64 + m * 16 + gl * 4;
    #pragma unroll
    for (int rg = 0; rg < 4; ++rg) {
      const int tok = ptok[base + rg];
      if (tok >= 0) {
        float* orow = out + (size_t)tok * EMB + ct * BN + wc * 64;
        #pragma unroll
        for (int nn = 0; nn < 4; ++nn)
          orow[nn * 16 + lrow] = acc[m][nn][rg];
      }
    }
  }
}

// Safety-net naive kernel (only if ws too small).
__global__ void naive_kernel(const float* __restrict__ X, const int* __restrict__ rel,
                             const float* __restrict__ W, float* __restrict__ out, int n) {
  int i = blockIdx.x;
  if (i >= n) return;
  int r = rel[i];
  const float* x = X + (size_t)i * EMB;
  const float* Wr = W + (size_t)r * EMB * EMB;
  for (int j = threadIdx.x; j < EMB; j += blockDim.x) {
    const float* w = Wr + (size_t)j * EMB;
    float s = 0.f;
    for (int k = 0; k < EMB; ++k) s += w[k] * x[k];
    out[(size_t)i * EMB + j] = s;
  }
}

extern "C" void kernel_launch(void* const* d_in, const int* in_sizes, int n_in,
                              void* d_out, int out_size, void* d_ws, size_t ws_size,
                              hipStream_t stream) {
  const float* X  = (const float*)d_in[0];
  const int* rel  = (const int*)d_in[1];
  const float* W  = (const float*)d_in[2];
  float* out      = (float*)d_out;
  const int n = in_sizes[1];
  const int welems = in_sizes[2];                 // n_rel * EMB * EMB
  const int padn = n + N_RELC * BM;
  const int nbh = (n + 255) / 256;                // histo blocks with tokens
  const int gpad = (padn + 255) / 256;            // histo grid (ptok fill)
  const int maxt = (n + BM - 1) / BM + N_RELC;
  const int maxtp = ((maxt + 3) / 4) * 4;         // grid = 2*maxtp -> %8==0

  const size_t ints = (size_t)32 + n + padn + maxtp + 2 * (size_t)nbh * N_RELC;
  const size_t offW = ((ints * sizeof(int) + 255) / 256) * 256;
  const size_t need = offW + (size_t)welems * 2;

  if (ws_size < need) {
    naive_kernel<<<n, 256, 0, stream>>>(X, rel, W, out, n);
    return;
  }

  int* pbase    = (int*)d_ws;            // 17 (+pad to 32)
  int* pos      = pbase + 32;            // n
  int* ptok     = pos + n;               // padn
  int* tinfo    = ptok + padn;           // maxtp
  int* blockcnt = tinfo + maxtp;         // nbh*16
  int* bbase    = blockcnt + (size_t)nbh * N_RELC;  // nbh*16
  unsigned short* Ws = (unsigned short*)((char*)d_ws + offW);

  const int wb = (welems / 8 + 255) / 256;          // convert-W blocks

  prep1<<<gpad + wb, 256, 0, stream>>>(rel, W, blockcnt, pos, ptok, Ws,
                                       n, padn, nbh, welems, gpad);
  prefix3<<<1, 256, 0, stream>>>(blockcnt, pbase, bbase, tinfo, nbh, maxtp);
  scatter2<<<(n + 255) / 256, 256, 0, stream>>>(rel, pos, bbase, ptok, n);

  gg19<<<2 * maxtp, 512, 0, stream>>>(X, Ws, pbase, tinfo, ptok, out);
}